// Round 1
// baseline (297.128 us; speedup 1.0000x reference)
//
#include <hip/hip_runtime.h>

// QLoRA NF4 forward: out[b,s,o] = 4.0 * sum_r (sum_i x[b,s,i]*W_A[r,i]) * W_B[o,r]
// B=4 S=2048 IN=4096 OUT=4096 R=8. All fp32.
//
// R4: two kernels.
//  - dequant: wA [8][4096], wBt [8][4096] (transposed, coalesced STORES;
//    gather moved to the tiny codes_B read side).
//  - fused lora: one kernel, 8 rows/block, 1024 blocks (4/CU).
//      phase 1: interm[8][8] via 2x2 wave split (row-half x i-half).
//               Cuts wA L1/L2 traffic 2x vs R3 (each i-half of wA read by
//               2 waves, not 4). interm lives in 256 B of LDS, not global.
//      phase 2: out rows in two halves of 4 -> peak ~90 VGPR, fits the
//               128-VGPR budget of __launch_bounds__(256,4). R3's lora_b
//               used (256,8) = 64-VGPR cap with an ~85-VGPR body -> spills.
//    Eliminates one launch + the interm global round-trip.

static __device__ __constant__ float NF4_TBL[16] = {
    -1.0f, -0.6961928009986877f, -0.5250730514526367f, -0.39491748809814453f,
    -0.28444138169288635f, -0.18477343022823334f, -0.09105003625154495f, 0.0f,
    0.07958029955625534f, 0.16093020141124725f, 0.24611230194568634f,
    0.33791524171829224f, 0.44070982933044434f, 0.5626170039176941f,
    0.7229568362236328f, 1.0f};

__global__ void nf4_dequant_kernel(const int* __restrict__ codesA,
                                   const float* __restrict__ absA,
                                   const int* __restrict__ codesB,
                                   const float* __restrict__ absB,
                                   float* __restrict__ wA,    // [8][4096]
                                   float* __restrict__ wBt,   // [8][4096] transposed
                                   int n) {
    int id = blockIdx.x * blockDim.x + threadIdx.x;
    if (id < n) {
        wA[id] = NF4_TBL[codesA[id] & 15] * absA[id >> 6];
        // wBt output-linear: id = r*4096 + o. codes_B flat index = o*8 + r,
        // absmax_B index = (o*8+r)>>6 = o>>3 (r<8). Stores coalesced.
        const int r = id >> 12;
        const int o = id & 4095;
        wBt[id] = NF4_TBL[codesB[o * 8 + r] & 15] * absB[o >> 3];
    }
}

// Fused lora_a + lora_b. Block = 8 rows, 256 threads (4 waves), 1024 blocks.
__global__ __launch_bounds__(256, 4) void lora_fused_kernel(
    const float* __restrict__ x,       // [8192][4096]
    const float* __restrict__ wA,      // [8][4096]
    const float* __restrict__ wBt,     // [8][4096]
    float* __restrict__ out) {         // [8192][4096]
    __shared__ __align__(16) float interm_s[2][8][8];   // [i-half][row][r]

    const int t    = threadIdx.x;
    const int wave = t >> 6;
    const int lane = t & 63;
    const int rh   = wave >> 1;        // row-half: rows rh*4 .. rh*4+3
    const int ih   = wave & 1;         // i-half:   float4 cols ih*512 ..
    const int row0 = blockIdx.x * 8;

    // ---------------- phase 1: interm = x @ wA^T (2x2 wave split) --------
    const float4* __restrict__ x4  =
        (const float4*)(x + (size_t)(row0 + rh * 4) * 4096);
    const float4* __restrict__ wA4 = (const float4*)wA;

    float acc[4][8];
    #pragma unroll
    for (int m = 0; m < 4; ++m)
        #pragma unroll
        for (int r = 0; r < 8; ++r) acc[m][r] = 0.f;

    #pragma unroll 2
    for (int c = 0; c < 8; ++c) {
        const int idx = ih * 512 + lane + 64 * c;     // coalesced per wave
        const float4 xa0 = x4[idx];
        const float4 xa1 = x4[1024 + idx];
        const float4 xa2 = x4[2048 + idx];
        const float4 xa3 = x4[3072 + idx];
        #pragma unroll
        for (int r = 0; r < 8; ++r) {
            const float4 w = wA4[r * 1024 + idx];     // L2-resident
            acc[0][r] += xa0.x * w.x + xa0.y * w.y + xa0.z * w.z + xa0.w * w.w;
            acc[1][r] += xa1.x * w.x + xa1.y * w.y + xa1.z * w.z + xa1.w * w.w;
            acc[2][r] += xa2.x * w.x + xa2.y * w.y + xa2.z * w.z + xa2.w * w.w;
            acc[3][r] += xa3.x * w.x + xa3.y * w.y + xa3.z * w.z + xa3.w * w.w;
        }
    }

    #pragma unroll
    for (int m = 0; m < 4; ++m) {
        #pragma unroll
        for (int r = 0; r < 8; ++r) {
            float v = acc[m][r];
            v += __shfl_down(v, 32, 64);
            v += __shfl_down(v, 16, 64);
            v += __shfl_down(v, 8, 64);
            v += __shfl_down(v, 4, 64);
            v += __shfl_down(v, 2, 64);
            v += __shfl_down(v, 1, 64);
            if (lane == 0) interm_s[ih][rh * 4 + m][r] = v;
        }
    }
    __syncthreads();

    // ---------------- phase 2: out = 4 * interm @ wBt ---------------------
    const float4* __restrict__ wt = (const float4*)wBt;          // [8][1024]
    const float4* s0 = (const float4*)&interm_s[0][0][0];        // 16 float4
    const float4* s1 = (const float4*)&interm_s[1][0][0];

    #pragma unroll 1
    for (int h = 0; h < 2; ++h) {      // two halves of 4 rows: caps VGPRs
        float im[4][8];
        #pragma unroll
        for (int m = 0; m < 4; ++m) {
            #pragma unroll
            for (int j = 0; j < 2; ++j) {
                const int q = (h * 4 + m) * 2 + j;
                const float4 a = s0[q];
                const float4 b = s1[q];
                im[m][4 * j + 0] = (a.x + b.x) * 4.0f;   // SCALING folded
                im[m][4 * j + 1] = (a.y + b.y) * 4.0f;
                im[m][4 * j + 2] = (a.z + b.z) * 4.0f;
                im[m][4 * j + 3] = (a.w + b.w) * 4.0f;
            }
        }
        #pragma unroll
        for (int k = 0; k < 4; ++k) {
            const int og = t + 256 * k;                  // float4 col group
            float4 w[8];
            #pragma unroll
            for (int r = 0; r < 8; ++r) w[r] = wt[r * 1024 + og];  // coalesced

            #pragma unroll
            for (int m = 0; m < 4; ++m) {
                float4 s;
                s.x = im[m][0] * w[0].x + im[m][1] * w[1].x + im[m][2] * w[2].x
                    + im[m][3] * w[3].x + im[m][4] * w[4].x + im[m][5] * w[5].x
                    + im[m][6] * w[6].x + im[m][7] * w[7].x;
                s.y = im[m][0] * w[0].y + im[m][1] * w[1].y + im[m][2] * w[2].y
                    + im[m][3] * w[3].y + im[m][4] * w[4].y + im[m][5] * w[5].y
                    + im[m][6] * w[6].y + im[m][7] * w[7].y;
                s.z = im[m][0] * w[0].z + im[m][1] * w[1].z + im[m][2] * w[2].z
                    + im[m][3] * w[3].z + im[m][4] * w[4].z + im[m][5] * w[5].z
                    + im[m][6] * w[6].z + im[m][7] * w[7].z;
                s.w = im[m][0] * w[0].w + im[m][1] * w[1].w + im[m][2] * w[2].w
                    + im[m][3] * w[3].w + im[m][4] * w[4].w + im[m][5] * w[5].w
                    + im[m][6] * w[6].w + im[m][7] * w[7].w;
                ((float4*)(out + (size_t)(row0 + h * 4 + m) * 4096))[og] = s;
            }
        }
    }
}

extern "C" void kernel_launch(void* const* d_in, const int* in_sizes, int n_in,
                              void* d_out, int out_size, void* d_ws, size_t ws_size,
                              hipStream_t stream) {
    const float* x        = (const float*)d_in[0];
    const int*   codes_A  = (const int*)d_in[1];
    const float* absmax_A = (const float*)d_in[2];
    const int*   codes_B  = (const int*)d_in[3];
    const float* absmax_B = (const float*)d_in[4];
    float* out = (float*)d_out;

    constexpr int NW = 8 * 4096;                 // elements per factor
    float* wA  = (float*)d_ws;                   // 128 KB
    float* wBt = (float*)d_ws + NW;              // 128 KB (transposed)

    nf4_dequant_kernel<<<(NW + 255) / 256, 256, 0, stream>>>(
        codes_A, absmax_A, codes_B, absmax_B, wA, wBt, NW);

    lora_fused_kernel<<<8192 / 8, 256, 0, stream>>>(x, wA, wBt, out);
}